// Round 10
// baseline (889.041 us; speedup 1.0000x reference)
//
#include <hip/hip_runtime.h>
#include <hip/hip_bf16.h>

// out[b,p,c] = sum_s x[b,s,c] * W[c,p,s] + bias[c,p]
// R10: MEASUREMENT ROUND on the best config (R5). The GEMM repeats its full
// compute REPS=3 times in one dispatch (idempotent) so it exceeds the ~400us
// rocprof top-5 cutoff and we finally get real counters. Two dispatches form an
// in-probe A/B: #1 FASTCVT (cheap round-half-up f32->bf16 pack), #2 RNE
// (__float2bfloat16, last writer -> final output unchanged vs R5).

#define SEQ   720
#define PRED  720
#define CH    321
#define BATCH 64
#define RTOT  (BATCH*SEQ)
#define BN1   48
#define NT1   15                /* 720/48 p-tiles */
#define BN    144               /* legacy fallback tiling */
#define NCHUNK 21
#define NGROUP (NCHUNK*5)

typedef __attribute__((ext_vector_type(8))) short short8;
typedef __attribute__((ext_vector_type(4))) float f32x4;
typedef __attribute__((ext_vector_type(4))) unsigned short us4;
typedef unsigned int u32;
typedef __attribute__((ext_vector_type(4))) u32 u32x4;

__device__ __forceinline__ short bf16bits(float f) {
    return __builtin_bit_cast(short, __float2bfloat16(f));
}
// round-half-up pack of two f32 -> one u32 of 2 bf16 (lo in low half)
__device__ __forceinline__ u32 pack2_rhu(float a, float b) {
    u32 ua = __builtin_bit_cast(u32, a) + 0x8000u;
    u32 ub = __builtin_bit_cast(u32, b) + 0x8000u;
    return (ua >> 16) | (ub & 0xFFFF0000u);
}

// async global->LDS DMA, 16B/lane. LDS dest = wave-uniform base (+lane*16 by HW).
__device__ __forceinline__ void gload16(const void* g, void* l) {
    __builtin_amdgcn_global_load_lds((const __attribute__((address_space(1))) u32*)g,
                                     (__attribute__((address_space(3))) u32*)l, 16, 0, 0);
}

// ---------------- x transpose: [46080][321] f32 -> [321][46080] bf16 ----------------
__global__ __launch_bounds__(256) void xpose_kernel(const float* __restrict__ x,
                                                    unsigned short* __restrict__ xt) {
    __shared__ float tile[64][33];
    const int bid = blockIdx.x;
    const int rt = bid % (RTOT/64);
    const int ct = bid / (RTOT/64);
    const int r0 = rt*64, c0 = ct*32;
    const int t  = threadIdx.x;
    const int cl = t & 31, rl0 = t >> 5;
    const int cg = c0 + cl;
    if (cg < CH) {
#pragma unroll
        for (int j = 0; j < 8; ++j) {
            int rl = rl0 + j*8;
            tile[rl][cl] = x[(size_t)(r0+rl)*CH + cg];
        }
    }
    __syncthreads();
#pragma unroll
    for (int j = 0; j < 8; ++j) {
        int idx = t + j*256;
        int c_l = idx >> 6;
        int r_l = idx & 63;
        if (c0 + c_l < CH)
            xt[(size_t)(c0+c_l)*RTOT + r0 + r_l] = (unsigned short)bf16bits(tile[r_l][c_l]);
    }
}

// ---------------- per-channel GEMM: 1 wave/block, BK=64, barrier-free (R5) ----------------
// LDS B: [48 rows][16 x 16B chunks] f32, phys chunk q of row r = logical q^(r&15).
// LDS A: [64 rows][8 x 16B chunks] bf16, phys chunk q of row r = logical q^(r&7).
// Stage = 12 B-DMAs + 8 A-DMAs per K-step. K: 11 full BK=64 steps + tail of 16.
template<bool STAGED, int REPS, bool FASTCVT>
__global__ __launch_bounds__(64) void gemm1w_kernel(
        const float* __restrict__ W, const float* __restrict__ bias,
        const unsigned short* __restrict__ xt, void* __restrict__ outp) {
    __shared__ __align__(16) float          Bl[2][BN1*64];   // 2 x 12 KB
    __shared__ __align__(16) unsigned short Al[2][64*64];    // 2 x  8 KB

    const int bid = blockIdx.x;
    const int c   = bid / NT1;
    const int pt  = bid % NT1;
    const int p0  = pt * BN1;
    const int lane = threadIdx.x & 63;
    const int row = lane & 15, kch = lane >> 4;

    const float* Wc          = W  + (size_t)c * ((size_t)PRED * SEQ);
    const unsigned short* Xc = xt + (size_t)c * RTOT;

    auto stage = [&](int buf, int kk) {
        const bool tail = (kk == 11);
#pragma unroll
        for (int i = 0; i < 12; ++i) {              // B: rows 4i..4i+3, 256B each
            const int r = 4*i + (lane >> 4);
            int sc = (lane & 15) ^ (r & 15);
            if (tail) sc &= 3;                      // clamp into s<720 (finite dup)
            gload16(Wc + (size_t)(p0 + r)*SEQ + kk*64 + sc*4, &Bl[buf][i*256]);
        }
#pragma unroll
        for (int i = 0; i < 8; ++i) {               // A: rows 8i..8i+7, 128B each
            const int r = 8*i + (lane >> 3);
            int sc = (lane & 7) ^ (r & 7);
            if (tail) sc &= 1;
            gload16(Xc + (size_t)r*SEQ + kk*64 + sc*8, &Al[buf][i*512]);
        }
    };

    f32x4 acc[4][3];

    auto compute = [&](int buf, int s, bool ztail) {
        short8 Af[4];
#pragma unroll
        for (int mi = 0; mi < 4; ++mi) {
            const int r2 = mi*16 + row;
            const int qa = (s*4 + kch) ^ (r2 & 7);
            Af[mi] = *reinterpret_cast<const short8*>(&Al[buf][r2*64 + qa*8]);
        }
        short8 Bf[3];
#pragma unroll
        for (int ni = 0; ni < 3; ++ni) {
            const int r2  = ni*16 + row;
            const int qlo = (s*8 + 2*kch)     ^ (r2 & 15);
            const int qhi = (s*8 + 2*kch + 1) ^ (r2 & 15);
            f32x4 lo = *reinterpret_cast<const f32x4*>(&Bl[buf][r2*64 + qlo*4]);
            f32x4 hi = *reinterpret_cast<const f32x4*>(&Bl[buf][r2*64 + qhi*4]);
            if (FASTCVT) {
                u32x4 w;
                w[0] = pack2_rhu(lo[0], lo[1]);
                w[1] = pack2_rhu(lo[2], lo[3]);
                w[2] = pack2_rhu(hi[0], hi[1]);
                w[3] = pack2_rhu(hi[2], hi[3]);
                Bf[ni] = __builtin_bit_cast(short8, w);
            } else {
                short8 v;
#pragma unroll
                for (int j = 0; j < 4; ++j) { v[j] = bf16bits(lo[j]); v[4+j] = bf16bits(hi[j]); }
                Bf[ni] = v;
            }
        }
        if (ztail && kch >= 2) {       // zero invalid K range (clamped data is finite)
            short8 z = {};
            Bf[0] = z; Bf[1] = z; Bf[2] = z;
        }
#pragma unroll
        for (int mi = 0; mi < 4; ++mi)
#pragma unroll
            for (int ni = 0; ni < 3; ++ni)
                acc[mi][ni] = __builtin_amdgcn_mfma_f32_16x16x32_bf16(
                                  Af[mi], Bf[ni], acc[mi][ni], 0, 0, 0);
    };

#pragma unroll 1
    for (int rep = 0; rep < REPS; ++rep) {
#pragma unroll
        for (int mi = 0; mi < 4; ++mi)
#pragma unroll
            for (int ni = 0; ni < 3; ++ni) acc[mi][ni] = f32x4{0.f, 0.f, 0.f, 0.f};

        stage(0, 0);
        stage(1, 1);
        for (int k = 0; k < 11; ++k) {
            const int buf = k & 1;
            // wait for stage(k)'s 20 DMAs; stage(k+1)'s 20 stay in flight
            asm volatile("s_waitcnt vmcnt(20)" ::: "memory");
            __builtin_amdgcn_sched_barrier(0);
            compute(buf, 0, false);
            compute(buf, 1, false);
            asm volatile("s_waitcnt lgkmcnt(0)" ::: "memory");   // my reads of buf done
            __builtin_amdgcn_sched_barrier(0);
            if (k <= 9) stage(buf, k + 2);          // refill just-freed buffer
        }
        {   // k=11 tail (16 cols), buf 1
            asm volatile("s_waitcnt vmcnt(0)" ::: "memory");
            __builtin_amdgcn_sched_barrier(0);
            compute(1, 0, true);
        }
    }

    // Epilogue. C/D map: col = lane&15, row = (lane>>4)*4 + reg.
    const int col   = lane & 15;
    const int rquad = lane >> 4;
    if (STAGED) {
        unsigned short* stg = (unsigned short*)outp;  // stage[c][p][b] bf16
#pragma unroll
        for (int ni = 0; ni < 3; ++ni) {
            const int p = p0 + ni*16 + col;
            const float bv = bias[(size_t)c*PRED + p];
#pragma unroll
            for (int mi = 0; mi < 4; ++mi) {
                us4 u;
#pragma unroll
                for (int r = 0; r < 4; ++r)
                    u[r] = (unsigned short)bf16bits(acc[mi][ni][r] + bv);
                *reinterpret_cast<us4*>(
                    stg + ((size_t)c*PRED + p)*BATCH + mi*16 + rquad*4) = u;
            }
        }
    } else {
        float* outf = (float*)outp;
#pragma unroll
        for (int ni = 0; ni < 3; ++ni) {
            const int p = p0 + ni*16 + col;
            const float bv = bias[(size_t)c*PRED + p];
#pragma unroll
            for (int mi = 0; mi < 4; ++mi)
#pragma unroll
                for (int r = 0; r < 4; ++r) {
                    const int b = mi*16 + rquad*4 + r;
                    outf[((size_t)b*PRED + p)*CH + c] = acc[mi][ni][r] + bv;
                }
        }
    }
}

// ---------------- fallback (no workspace): gather x directly, scattered stores ----------------
__global__ __launch_bounds__(192) void gemm_fallback_kernel(
        const float* __restrict__ W, const float* __restrict__ bias,
        const float* __restrict__ x, float* __restrict__ outp) {
    const int bid  = blockIdx.x;
    const int g    = (bid & 7) + 8*((bid >> 3) >> 4);
    const int coff = (bid >> 3) & 15;
    if (g >= NGROUP) return;
    const int c  = (g % NCHUNK)*16 + coff;
    if (c >= CH) return;
    const int p0 = (g / NCHUNK) * BN;
    const int tid = threadIdx.x, wv = tid >> 6, lane = tid & 63;
    const int row = lane & 15, kch = lane >> 4, nb = p0 + wv*48;
    const float* Wc = W + (size_t)c * ((size_t)PRED * SEQ);
    f32x4 acc[4][3] = {};
    for (int k = 0; k < 23; ++k) {
        const int kc = (k == 22) ? (kch & 1) : kch;
        const int s  = k*32 + kc*8;
        short8 Af[4], Bf[3];
#pragma unroll
        for (int mi = 0; mi < 4; ++mi) {
            short8 v;
#pragma unroll
            for (int j = 0; j < 8; ++j)
                v[j] = bf16bits(x[((size_t)(mi*16 + row)*SEQ + s + j)*CH + c]);
            Af[mi] = v;
        }
#pragma unroll
        for (int ni = 0; ni < 3; ++ni) {
            const float* p = Wc + (size_t)(nb + ni*16 + row)*SEQ + s;
            short8 v;
#pragma unroll
            for (int j = 0; j < 4; ++j) { v[j] = bf16bits(p[j]); v[4+j] = bf16bits(p[4+j]); }
            Bf[ni] = v;
        }
        if (k == 22 && kch >= 2) { short8 z = {}; Bf[0] = z; Bf[1] = z; Bf[2] = z; }
#pragma unroll
        for (int mi = 0; mi < 4; ++mi)
#pragma unroll
            for (int ni = 0; ni < 3; ++ni)
                acc[mi][ni] = __builtin_amdgcn_mfma_f32_16x16x32_bf16(
                                  Af[mi], Bf[ni], acc[mi][ni], 0, 0, 0);
    }
    const int col = lane & 15, rquad = lane >> 4;
#pragma unroll
    for (int ni = 0; ni < 3; ++ni) {
        const int p = nb + ni*16 + col;
        const float bv = bias[(size_t)c*PRED + p];
#pragma unroll
        for (int mi = 0; mi < 4; ++mi)
#pragma unroll
            for (int r = 0; r < 4; ++r)
                outp[((size_t)(mi*16 + rquad*4 + r)*PRED + p)*CH + c] = acc[mi][ni][r] + bv;
    }
}

// ---------------- unstage: stage[C][P][B] bf16 -> out[B][P][C] f32 ----------------
__global__ __launch_bounds__(256) void unstage_kernel(const unsigned short* __restrict__ stage,
                                                      float* __restrict__ out) {
    const int p  = blockIdx.x;
    const int c0 = blockIdx.y * 128;
    const int cn = (CH - c0 < 128) ? (CH - c0) : 128;
    __shared__ float tl[128][65];
    const int t = threadIdx.x;
    {
        const int b   = t & 63;
        const int ci0 = t >> 6;
        for (int ci = ci0; ci < cn; ci += 4) {
            unsigned short us = stage[((size_t)(c0+ci)*PRED + p)*BATCH + b];
            tl[ci][b] = __builtin_bit_cast(float, (u32)us << 16);
        }
    }
    __syncthreads();
    {
        const int cl = t & 127;
        const int b0 = t >> 7;
        if (cl < cn)
#pragma unroll
            for (int bb = b0; bb < BATCH; bb += 2)
                out[((size_t)bb*PRED + p)*CH + c0 + cl] = tl[cl][bb];
    }
}

extern "C" void kernel_launch(void* const* d_in, const int* in_sizes, int n_in,
                              void* d_out, int out_size, void* d_ws, size_t ws_size,
                              hipStream_t stream) {
    const float* x    = (const float*)d_in[0];
    const float* W    = (const float*)d_in[1];
    const float* bias = (const float*)d_in[2];
    float* out        = (float*)d_out;

    const size_t xt_bytes    = (size_t)CH * RTOT * sizeof(unsigned short);        // 29.6 MB
    const size_t stage_bytes = (size_t)CH * PRED * BATCH * sizeof(unsigned short);// 29.6 MB

    if (ws_size >= xt_bytes + stage_bytes) {
        unsigned short* xtp = (unsigned short*)d_ws;
        unsigned short* stg = (unsigned short*)((char*)d_ws + xt_bytes);
        xpose_kernel<<<dim3((RTOT/64) * 11), dim3(256), 0, stream>>>(x, xtp);
        // A/B probe: FASTCVT first (values overwritten), RNE second (last writer ->
        // final output identical to R5's proven absmax).
        gemm1w_kernel<true, 3, true ><<<dim3(CH * NT1), dim3(64), 0, stream>>>(W, bias, xtp, stg);
        gemm1w_kernel<true, 3, false><<<dim3(CH * NT1), dim3(64), 0, stream>>>(W, bias, xtp, stg);
        unstage_kernel<<<dim3(PRED, 3), dim3(256), 0, stream>>>(stg, out);
    } else if (ws_size >= xt_bytes) {
        unsigned short* xtp = (unsigned short*)d_ws;
        xpose_kernel<<<dim3((RTOT/64) * 11), dim3(256), 0, stream>>>(x, xtp);
        gemm1w_kernel<false, 1, false><<<dim3(CH * NT1), dim3(64), 0, stream>>>(W, bias, xtp, out);
    } else {
        gemm_fallback_kernel<<<dim3(8 * 14 * 16), dim3(192), 0, stream>>>(
            W, bias, x, out);
    }
}

// Round 11
// 214.929 us; speedup vs baseline: 4.1364x; 4.1364x over previous
//
#include <hip/hip_runtime.h>
#include <hip/hip_bf16.h>

// out[b,p,c] = sum_s x[b,s,c] * W[c,p,s] + bias[c,p]
// x: [64,720,321] f32, W: [321,720,720] f32, bias: [321,720] f32, out: [64,720,321] f32
// R11: per-CU LOAD-PATH model (R10 counters: path = W 666MB + A-rereads 444MB =
// 7.35 TB/s = 9.8 B/cyc/CU == m13 ceiling; MfmaUtil 5.9%, VALUBusy 13.6% -> only
// the path is saturated). Cut path bytes: BN 48->80 (9 p-tiles, A re-read 15->9x,
// path 1.11GB->0.93GB). Keep R5's barrier-free 1-wave counted-vmcnt structure
// (best measured path rate). LDS 57.3KB -> 2 blocks/CU. vmcnt(28) steady-state,
// prologue 56 DMAs < 63 ceiling.

#define SEQ   720
#define PRED  720
#define CH    321
#define BATCH 64
#define RTOT  (BATCH*SEQ)
#define BNW   80
#define NTW   9                 /* 720/80 p-tiles */
#define BN    144               /* legacy fallback tiling */
#define NCHUNK 21
#define NGROUP (NCHUNK*5)

typedef __attribute__((ext_vector_type(8))) short short8;
typedef __attribute__((ext_vector_type(4))) float f32x4;
typedef __attribute__((ext_vector_type(4))) unsigned short us4;
typedef unsigned int u32;

__device__ __forceinline__ short bf16bits(float f) {
    return __builtin_bit_cast(short, __float2bfloat16(f));
}

// async global->LDS DMA, 16B/lane. LDS dest = wave-uniform base (+lane*16 by HW);
// global src is per-lane.
__device__ __forceinline__ void gload16(const void* g, void* l) {
    __builtin_amdgcn_global_load_lds((const __attribute__((address_space(1))) u32*)g,
                                     (__attribute__((address_space(3))) u32*)l, 16, 0, 0);
}

// ---------------- x transpose: [46080][321] f32 -> [321][46080] bf16 ----------------
__global__ __launch_bounds__(256) void xpose_kernel(const float* __restrict__ x,
                                                    unsigned short* __restrict__ xt) {
    __shared__ float tile[64][33];
    const int bid = blockIdx.x;
    const int rt = bid % (RTOT/64);
    const int ct = bid / (RTOT/64);
    const int r0 = rt*64, c0 = ct*32;
    const int t  = threadIdx.x;
    const int cl = t & 31, rl0 = t >> 5;
    const int cg = c0 + cl;
    if (cg < CH) {
#pragma unroll
        for (int j = 0; j < 8; ++j) {
            int rl = rl0 + j*8;
            tile[rl][cl] = x[(size_t)(r0+rl)*CH + cg];
        }
    }
    __syncthreads();
#pragma unroll
    for (int j = 0; j < 8; ++j) {
        int idx = t + j*256;
        int c_l = idx >> 6;
        int r_l = idx & 63;
        if (c0 + c_l < CH)
            xt[(size_t)(c0+c_l)*RTOT + r0 + r_l] = (unsigned short)bf16bits(tile[r_l][c_l]);
    }
}

// ---------------- per-channel GEMM: 1 wave/block, BN=80, BK=64, barrier-free ----------------
// LDS B: [80 rows][16 x 16B chunks] f32, phys chunk q of row r = logical q^(r&15).
// LDS A: [64 rows][8 x 16B chunks] bf16, phys chunk q of row r = logical q^(r&7).
// Stage = 20 B-DMAs + 8 A-DMAs per K-step (1KB each: 4 rows x 256B / 8 rows x 128B).
// K: 11 full BK=64 steps + tail of 16 (clamped sources, kch>=2 B-frags zeroed).
template<bool STAGED>
__global__ __launch_bounds__(64) void gemm1w_kernel(
        const float* __restrict__ W, const float* __restrict__ bias,
        const unsigned short* __restrict__ xt, void* __restrict__ outp) {
    __shared__ __align__(16) float          Bl[2][BNW*64];   // 2 x 20 KB
    __shared__ __align__(16) unsigned short Al[2][64*64];    // 2 x  8 KB (total 57.3KB)

    const int bid = blockIdx.x;
    const int c   = bid / NTW;
    const int pt  = bid % NTW;
    const int p0  = pt * BNW;
    const int lane = threadIdx.x & 63;
    const int row = lane & 15, kch = lane >> 4;

    const float* Wc          = W  + (size_t)c * ((size_t)PRED * SEQ);
    const unsigned short* Xc = xt + (size_t)c * RTOT;

    auto stage = [&](int buf, int kk) {
        const bool tail = (kk == 11);
#pragma unroll
        for (int i = 0; i < 20; ++i) {              // B: rows 4i..4i+3, 256B each
            const int r = 4*i + (lane >> 4);
            int sc = (lane & 15) ^ (r & 15);
            if (tail) sc &= 3;                      // clamp into s<720 (finite dup)
            gload16(Wc + (size_t)(p0 + r)*SEQ + kk*64 + sc*4, &Bl[buf][i*256]);
        }
#pragma unroll
        for (int i = 0; i < 8; ++i) {               // A: rows 8i..8i+7, 128B each
            const int r = 8*i + (lane >> 3);
            int sc = (lane & 7) ^ (r & 7);
            if (tail) sc &= 1;
            gload16(Xc + (size_t)r*SEQ + kk*64 + sc*8, &Al[buf][i*512]);
        }
    };

    f32x4 acc[4][5] = {};

    auto compute = [&](int buf, int s, bool ztail) {
        short8 Af[4];
#pragma unroll
        for (int mi = 0; mi < 4; ++mi) {
            const int r2 = mi*16 + row;
            const int qa = (s*4 + kch) ^ (r2 & 7);
            Af[mi] = *reinterpret_cast<const short8*>(&Al[buf][r2*64 + qa*8]);
        }
        short8 Bf[5];
#pragma unroll
        for (int ni = 0; ni < 5; ++ni) {
            const int r2  = ni*16 + row;
            const int qlo = (s*8 + 2*kch)     ^ (r2 & 15);
            const int qhi = (s*8 + 2*kch + 1) ^ (r2 & 15);
            f32x4 lo = *reinterpret_cast<const f32x4*>(&Bl[buf][r2*64 + qlo*4]);
            f32x4 hi = *reinterpret_cast<const f32x4*>(&Bl[buf][r2*64 + qhi*4]);
            short8 v;
#pragma unroll
            for (int j = 0; j < 4; ++j) { v[j] = bf16bits(lo[j]); v[4+j] = bf16bits(hi[j]); }
            Bf[ni] = v;
        }
        if (ztail && kch >= 2) {       // zero invalid K range (clamped data is finite)
            short8 z = {};
#pragma unroll
            for (int ni = 0; ni < 5; ++ni) Bf[ni] = z;
        }
#pragma unroll
        for (int mi = 0; mi < 4; ++mi)
#pragma unroll
            for (int ni = 0; ni < 5; ++ni)
                acc[mi][ni] = __builtin_amdgcn_mfma_f32_16x16x32_bf16(
                                  Af[mi], Bf[ni], acc[mi][ni], 0, 0, 0);
    };

    stage(0, 0);             // 28 outstanding
    stage(1, 1);             // 56 outstanding (< 63 vmcnt ceiling)
    for (int k = 0; k < 11; ++k) {
        const int buf = k & 1;
        // wait for stage(k)'s 28 DMAs; stage(k+1)'s 28 stay in flight
        asm volatile("s_waitcnt vmcnt(28)" ::: "memory");
        __builtin_amdgcn_sched_barrier(0);
        compute(buf, 0, false);
        compute(buf, 1, false);
        asm volatile("s_waitcnt lgkmcnt(0)" ::: "memory");   // my reads of buf done
        __builtin_amdgcn_sched_barrier(0);
        if (k <= 9) stage(buf, k + 2);               // refill just-freed buffer
    }
    {   // k=11 tail (16 cols), buf 1
        asm volatile("s_waitcnt vmcnt(0)" ::: "memory");
        __builtin_amdgcn_sched_barrier(0);
        compute(1, 0, true);
    }

    // Epilogue. C/D map: col = lane&15, row = (lane>>4)*4 + reg.
    const int col   = lane & 15;
    const int rquad = lane >> 4;
    if (STAGED) {
        unsigned short* stg = (unsigned short*)outp;  // stage[c][p][b] bf16
#pragma unroll
        for (int ni = 0; ni < 5; ++ni) {
            const int p = p0 + ni*16 + col;
            const float bv = bias[(size_t)c*PRED + p];
#pragma unroll
            for (int mi = 0; mi < 4; ++mi) {
                us4 u;
#pragma unroll
                for (int r = 0; r < 4; ++r)
                    u[r] = (unsigned short)bf16bits(acc[mi][ni][r] + bv);
                *reinterpret_cast<us4*>(
                    stg + ((size_t)c*PRED + p)*BATCH + mi*16 + rquad*4) = u;
            }
        }
    } else {
        float* outf = (float*)outp;
#pragma unroll
        for (int ni = 0; ni < 5; ++ni) {
            const int p = p0 + ni*16 + col;
            const float bv = bias[(size_t)c*PRED + p];
#pragma unroll
            for (int mi = 0; mi < 4; ++mi)
#pragma unroll
                for (int r = 0; r < 4; ++r) {
                    const int b = mi*16 + rquad*4 + r;
                    outf[((size_t)b*PRED + p)*CH + c] = acc[mi][ni][r] + bv;
                }
        }
    }
}

// ---------------- fallback (no workspace): gather x directly, scattered stores ----------------
__global__ __launch_bounds__(192) void gemm_fallback_kernel(
        const float* __restrict__ W, const float* __restrict__ bias,
        const float* __restrict__ x, float* __restrict__ outp) {
    const int bid  = blockIdx.x;
    const int g    = (bid & 7) + 8*((bid >> 3) >> 4);
    const int coff = (bid >> 3) & 15;
    if (g >= NGROUP) return;
    const int c  = (g % NCHUNK)*16 + coff;
    if (c >= CH) return;
    const int p0 = (g / NCHUNK) * BN;
    const int tid = threadIdx.x, wv = tid >> 6, lane = tid & 63;
    const int row = lane & 15, kch = lane >> 4, nb = p0 + wv*48;
    const float* Wc = W + (size_t)c * ((size_t)PRED * SEQ);
    f32x4 acc[4][3] = {};
    for (int k = 0; k < 23; ++k) {
        const int kc = (k == 22) ? (kch & 1) : kch;
        const int s  = k*32 + kc*8;
        short8 Af[4], Bf[3];
#pragma unroll
        for (int mi = 0; mi < 4; ++mi) {
            short8 v;
#pragma unroll
            for (int j = 0; j < 8; ++j)
                v[j] = bf16bits(x[((size_t)(mi*16 + row)*SEQ + s + j)*CH + c]);
            Af[mi] = v;
        }
#pragma unroll
        for (int ni = 0; ni < 3; ++ni) {
            const float* p = Wc + (size_t)(nb + ni*16 + row)*SEQ + s;
            short8 v;
#pragma unroll
            for (int j = 0; j < 4; ++j) { v[j] = bf16bits(p[j]); v[4+j] = bf16bits(p[4+j]); }
            Bf[ni] = v;
        }
        if (k == 22 && kch >= 2) { short8 z = {}; Bf[0] = z; Bf[1] = z; Bf[2] = z; }
#pragma unroll
        for (int mi = 0; mi < 4; ++mi)
#pragma unroll
            for (int ni = 0; ni < 3; ++ni)
                acc[mi][ni] = __builtin_amdgcn_mfma_f32_16x16x32_bf16(
                                  Af[mi], Bf[ni], acc[mi][ni], 0, 0, 0);
    }
    const int col = lane & 15, rquad = lane >> 4;
#pragma unroll
    for (int ni = 0; ni < 3; ++ni) {
        const int p = nb + ni*16 + col;
        const float bv = bias[(size_t)c*PRED + p];
#pragma unroll
        for (int mi = 0; mi < 4; ++mi)
#pragma unroll
            for (int r = 0; r < 4; ++r)
                outp[((size_t)(mi*16 + rquad*4 + r)*PRED + p)*CH + c] = acc[mi][ni][r] + bv;
    }
}

// ---------------- unstage: stage[C][P][B] bf16 -> out[B][P][C] f32 ----------------
__global__ __launch_bounds__(256) void unstage_kernel(const unsigned short* __restrict__ stage,
                                                      float* __restrict__ out) {
    const int p  = blockIdx.x;
    const int c0 = blockIdx.y * 128;
    const int cn = (CH - c0 < 128) ? (CH - c0) : 128;
    __shared__ float tl[128][65];
    const int t = threadIdx.x;
    {
        const int b   = t & 63;
        const int ci0 = t >> 6;
        for (int ci = ci0; ci < cn; ci += 4) {
            unsigned short us = stage[((size_t)(c0+ci)*PRED + p)*BATCH + b];
            tl[ci][b] = __builtin_bit_cast(float, (u32)us << 16);
        }
    }
    __syncthreads();
    {
        const int cl = t & 127;
        const int b0 = t >> 7;
        if (cl < cn)
#pragma unroll
            for (int bb = b0; bb < BATCH; bb += 2)
                out[((size_t)bb*PRED + p)*CH + c0 + cl] = tl[cl][bb];
    }
}

extern "C" void kernel_launch(void* const* d_in, const int* in_sizes, int n_in,
                              void* d_out, int out_size, void* d_ws, size_t ws_size,
                              hipStream_t stream) {
    const float* x    = (const float*)d_in[0];
    const float* W    = (const float*)d_in[1];
    const float* bias = (const float*)d_in[2];
    float* out        = (float*)d_out;

    const size_t xt_bytes    = (size_t)CH * RTOT * sizeof(unsigned short);        // 29.6 MB
    const size_t stage_bytes = (size_t)CH * PRED * BATCH * sizeof(unsigned short);// 29.6 MB

    if (ws_size >= xt_bytes + stage_bytes) {
        unsigned short* xtp = (unsigned short*)d_ws;
        unsigned short* stg = (unsigned short*)((char*)d_ws + xt_bytes);
        xpose_kernel<<<dim3((RTOT/64) * 11), dim3(256), 0, stream>>>(x, xtp);
        gemm1w_kernel<true><<<dim3(CH * NTW), dim3(64), 0, stream>>>(W, bias, xtp, stg);
        unstage_kernel<<<dim3(PRED, 3), dim3(256), 0, stream>>>(stg, out);
    } else if (ws_size >= xt_bytes) {
        unsigned short* xtp = (unsigned short*)d_ws;
        xpose_kernel<<<dim3((RTOT/64) * 11), dim3(256), 0, stream>>>(x, xtp);
        gemm1w_kernel<false><<<dim3(CH * NTW), dim3(64), 0, stream>>>(W, bias, xtp, out);
    } else {
        gemm_fallback_kernel<<<dim3(8 * 14 * 16), dim3(192), 0, stream>>>(
            W, bias, x, out);
    }
}